// Round 1
// baseline (849.659 us; speedup 1.0000x reference)
//
#include <hip/hip_runtime.h>
#include <hip/hip_bf16.h>
#include <stdint.h>

#define DEVI __device__ __forceinline__

using bf16 = __hip_bfloat16;

typedef __bf16 bf16x8 __attribute__((ext_vector_type(8)));
typedef float f32x4 __attribute__((ext_vector_type(4)));

constexpr int BATCH = 4, NH = 16, SEQ = 2048, HD = 128, DMODEL = 2048;
constexpr int MROWS = BATCH * SEQ;  // 8192

DEVI f32x4 mfma16(uint4 a, uint4 b, f32x4 c) {
  return __builtin_amdgcn_mfma_f32_16x16x32_bf16(
      __builtin_bit_cast(bf16x8, a), __builtin_bit_cast(bf16x8, b), c, 0, 0, 0);
}

DEVI unsigned pack2(float a, float b) {
  __hip_bfloat16 ha = __float2bfloat16(a), hb = __float2bfloat16(b);
  unsigned short ua = __builtin_bit_cast(unsigned short, ha);
  unsigned short ub = __builtin_bit_cast(unsigned short, hb);
  return ((unsigned)ub << 16) | (unsigned)ua;
}

DEVI void gload16(const void* g, void* l) {
  auto gp = reinterpret_cast<__attribute__((address_space(1))) unsigned int*>(
      reinterpret_cast<uintptr_t>(g));
  auto lp = reinterpret_cast<__attribute__((address_space(3))) unsigned int*>(
      reinterpret_cast<uintptr_t>(l));
  __builtin_amdgcn_global_load_lds(gp, lp, 16, 0, 0);
}

// ---------------- cast x (fp32 -> bf16), vectorized ----------------
__global__ void cast_x_kernel(const float* __restrict__ in, bf16* __restrict__ out, int n8) {
  for (int i = blockIdx.x * blockDim.x + threadIdx.x; i < n8; i += gridDim.x * blockDim.x) {
    const float4* p = (const float4*)in + (size_t)i * 2;
    float4 a = p[0], b = p[1];
    uint4 u;
    u.x = pack2(a.x, a.y);
    u.y = pack2(a.z, a.w);
    u.z = pack2(b.x, b.y);
    u.w = pack2(b.z, b.w);
    *((uint4*)out + i) = u;
  }
}

// ------------- transpose-cast W [K][N] fp32 -> Wt [N][K] bf16 -------------
__global__ void transpose_w_kernel(const float* __restrict__ W0, const float* __restrict__ W1,
                                   const float* __restrict__ W2, bf16* __restrict__ WtBase) {
  const int z = blockIdx.z;
  const float* W = (z == 0) ? W0 : (z == 1) ? W1 : W2;
  bf16* Wt = WtBase + (size_t)z * DMODEL * DMODEL;
  __shared__ float tile[64][65];
  const int k0 = blockIdx.x * 64, n0 = blockIdx.y * 64;
  const int tid = threadIdx.x;
  for (int i = tid; i < 4096; i += 256) {
    int r = i >> 6, c = i & 63;
    tile[r][c] = W[(size_t)(k0 + r) * DMODEL + n0 + c];
  }
  __syncthreads();
  for (int i = tid; i < 4096; i += 256) {
    int r = i >> 6, c = i & 63;  // r = n index, c = k index
    Wt[(size_t)(n0 + r) * DMODEL + k0 + c] = __float2bfloat16(tile[c][r]);
  }
}

// ---------------- bf16 GEMM: C[m][n] = sum_k A[m][k] * Bt[n][k] + bias[n] ---------------
// A: [MROWS][DMODEL], Bt: [DMODEL][DMODEL] (W transposed).
// transposed==0: Cout[bh][s][d]  (Q, K layout)
// transposed==1: Cout[bh][d][s]  (V^T layout)
__global__ __launch_bounds__(256) void gemm_bf16(
    const bf16* __restrict__ A, const bf16* __restrict__ Bt,
    const float* __restrict__ bias, bf16* __restrict__ Cout, int transposed) {
  __shared__ __align__(16) bf16 As[128][32];
  __shared__ __align__(16) bf16 Bs[128][32];
  const int tid = threadIdx.x;
  const int lane = tid & 63, wave = tid >> 6;
  const int lr = lane & 15, lg = lane >> 4;
  const int m0 = blockIdx.x * 128, n0 = blockIdx.y * 128;
  const int wr = wave >> 1, wc = wave & 1;

  f32x4 acc[4][4];
#pragma unroll
  for (int i = 0; i < 4; ++i)
#pragma unroll
    for (int j = 0; j < 4; ++j) acc[i][j] = (f32x4){0.f, 0.f, 0.f, 0.f};

  const char* ag = (const char*)(A + (size_t)(m0 + (tid >> 2)) * DMODEL) + (tid & 3) * 16;
  const char* bg = (const char*)(Bt + (size_t)(n0 + (tid >> 2)) * DMODEL) + (tid & 3) * 16;
  char* asw = (char*)As + wave * 1024;
  char* bsw = (char*)Bs + wave * 1024;
  constexpr size_t rowadv = (size_t)64 * DMODEL * 2;

  for (int k0 = 0; k0 < DMODEL; k0 += 32) {
    gload16(ag + k0 * 2, asw);
    gload16(ag + k0 * 2 + rowadv, asw + 4096);
    gload16(bg + k0 * 2, bsw);
    gload16(bg + k0 * 2 + rowadv, bsw + 4096);
    __syncthreads();
    uint4 af[4], bfr[4];
#pragma unroll
    for (int i = 0; i < 4; ++i) af[i] = *(const uint4*)&As[wr * 64 + i * 16 + lr][lg * 8];
#pragma unroll
    for (int j = 0; j < 4; ++j) bfr[j] = *(const uint4*)&Bs[wc * 64 + j * 16 + lr][lg * 8];
#pragma unroll
    for (int i = 0; i < 4; ++i)
#pragma unroll
      for (int j = 0; j < 4; ++j) acc[i][j] = mfma16(af[i], bfr[j], acc[i][j]);
    __syncthreads();
  }

  float bvals[4];
#pragma unroll
  for (int nf = 0; nf < 4; ++nf) bvals[nf] = bias[n0 + wc * 64 + nf * 16 + lr];

  const int bh = ((m0 >> 11) << 4) | (n0 >> 7);
  const int sbase = (m0 & 2047) + wr * 64;
  if (!transposed) {
    bf16* base = Cout + (size_t)bh * SEQ * HD;
#pragma unroll
    for (int mf = 0; mf < 4; ++mf)
#pragma unroll
      for (int nf = 0; nf < 4; ++nf) {
        int d = wc * 64 + nf * 16 + lr;
#pragma unroll
        for (int jj = 0; jj < 4; ++jj) {
          int s = sbase + mf * 16 + lg * 4 + jj;
          base[(size_t)s * HD + d] = __float2bfloat16(acc[mf][nf][jj] + bvals[nf]);
        }
      }
  } else {
    bf16* base = Cout + (size_t)bh * HD * SEQ;
#pragma unroll
    for (int mf = 0; mf < 4; ++mf)
#pragma unroll
      for (int nf = 0; nf < 4; ++nf) {
        int d = wc * 64 + nf * 16 + lr;
        int s0 = sbase + mf * 16 + lg * 4;
        uint2 u;
        u.x = pack2(acc[mf][nf][0] + bvals[nf], acc[mf][nf][1] + bvals[nf]);
        u.y = pack2(acc[mf][nf][2] + bvals[nf], acc[mf][nf][3] + bvals[nf]);
        *(uint2*)&base[(size_t)d * SEQ + s0] = u;
      }
  }
}

// ---------------- flash attention, causal ----------------
// Q,K: [BH][S][D] bf16;  Vt: [BH][D][S] bf16;  out: [B][S][H*D] fp32
// 4 independent waves per block, 32 q-rows per wave, KV tiles of 64.
__global__ __launch_bounds__(256) void attn_kernel(
    const bf16* __restrict__ Q, const bf16* __restrict__ K,
    const bf16* __restrict__ Vt, float* __restrict__ out) {
  const int lane = threadIdx.x & 63;
  const int wave = threadIdx.x >> 6;
  const int lr = lane & 15, lg = lane >> 4;

  // XCD swizzle: keep all 16 q-tiles of one (b,h) on one XCD.
  const int lid = blockIdx.y * gridDim.x + blockIdx.x;  // 0..1023
  const int xcd = lid & 7, slot = lid >> 3;
  const int bh = xcd * 8 + (slot >> 4);
  const int qtile = slot & 15;
  const int b = bh >> 4, h = bh & 15;
  const int q0 = qtile * 128 + wave * 32;

  const bf16* Qp = Q + (size_t)bh * SEQ * HD;
  const bf16* Kp = K + (size_t)bh * SEQ * HD;
  const bf16* Vp = Vt + (size_t)bh * HD * SEQ;

  // Q fragments (B-operand): q col = lr, d chunk = dc*32 + lg*8
  uint4 qfrag[2][4];
#pragma unroll
  for (int qf = 0; qf < 2; ++qf) {
    const bf16* qrow = Qp + (size_t)(q0 + qf * 16 + lr) * HD + lg * 8;
#pragma unroll
    for (int dc = 0; dc < 4; ++dc) qfrag[qf][dc] = *(const uint4*)(qrow + dc * 32);
  }

  f32x4 acc[8][2];
#pragma unroll
  for (int df = 0; df < 8; ++df) {
    acc[df][0] = (f32x4){0.f, 0.f, 0.f, 0.f};
    acc[df][1] = (f32x4){0.f, 0.f, 0.f, 0.f};
  }
  float m_run[2] = {-1e30f, -1e30f};
  float l_run[2] = {0.f, 0.f};

  __shared__ __align__(16) char plds[4][4096];  // per-wave P buffer [32 q][64 kv] bf16, XOR-swizzled
  char* pbase = &plds[wave][0];

  const float scale = 0.08838834764831845f;  // 1/sqrt(128)
  const int qg[2] = {q0 + lr, q0 + 16 + lr};
  const int ntiles = (q0 + 95) >> 6;

  for (int t = 0; t < ntiles; ++t) {
    const int kv0 = t << 6;
    // ---- S^T = K * Q^T ----
    f32x4 sfr[4][2];
#pragma unroll
    for (int kvf = 0; kvf < 4; ++kvf) {
      sfr[kvf][0] = (f32x4){0.f, 0.f, 0.f, 0.f};
      sfr[kvf][1] = (f32x4){0.f, 0.f, 0.f, 0.f};
      const bf16* krow = Kp + (size_t)(kv0 + kvf * 16 + lr) * HD + lg * 8;
#pragma unroll
      for (int dc = 0; dc < 4; ++dc) {
        uint4 ka = *(const uint4*)(krow + dc * 32);
        sfr[kvf][0] = mfma16(ka, qfrag[0][dc], sfr[kvf][0]);
        sfr[kvf][1] = mfma16(ka, qfrag[1][dc], sfr[kvf][1]);
      }
    }
    // ---- online softmax per qf (lane owns q-row qg[qf], kv slice lg*4+j per kvf) ----
#pragma unroll
    for (int qf = 0; qf < 2; ++qf) {
      float mx = -1e30f;
#pragma unroll
      for (int kvf = 0; kvf < 4; ++kvf)
#pragma unroll
        for (int j = 0; j < 4; ++j) {
          int kvgl = kv0 + kvf * 16 + lg * 4 + j;
          float v = sfr[kvf][qf][j] * scale;
          v = (kvgl <= qg[qf]) ? v : -1e30f;
          sfr[kvf][qf][j] = v;
          mx = fmaxf(mx, v);
        }
      mx = fmaxf(mx, __shfl_xor(mx, 16));
      mx = fmaxf(mx, __shfl_xor(mx, 32));
      float mnew = fmaxf(m_run[qf], mx);
      float corr = __expf(m_run[qf] - mnew);
      m_run[qf] = mnew;
      float ps = 0.f;
      const int qlocal = qf * 16 + lr;
      const unsigned sw = ((unsigned)(qlocal & 7)) << 4;
      char* bp = pbase + qlocal * 128;
#pragma unroll
      for (int kvf = 0; kvf < 4; ++kvf) {
        float p0 = __expf(sfr[kvf][qf][0] - mnew);
        float p1 = __expf(sfr[kvf][qf][1] - mnew);
        float p2 = __expf(sfr[kvf][qf][2] - mnew);
        float p3 = __expf(sfr[kvf][qf][3] - mnew);
        ps += p0 + p1 + p2 + p3;
        unsigned off = ((unsigned)(kvf * 32 + lg * 8)) ^ sw;
        *(unsigned*)(bp + off) = pack2(p0, p1);
        *(unsigned*)(bp + off + 4) = pack2(p2, p3);
      }
      ps += __shfl_xor(ps, 16);
      ps += __shfl_xor(ps, 32);
      l_run[qf] = l_run[qf] * corr + ps;
#pragma unroll
      for (int df = 0; df < 8; ++df) acc[df][qf] *= corr;
    }
    // cross-lane LDS RAW within wave: drain DS queue, fence compiler reordering
    asm volatile("s_waitcnt lgkmcnt(0)" ::: "memory");
    // ---- read P^T B-fragments ----
    uint4 pb[2][2];  // [kc][qf]
#pragma unroll
    for (int qf = 0; qf < 2; ++qf) {
      const int qlocal = qf * 16 + lr;
      const unsigned sw = ((unsigned)(qlocal & 7)) << 4;
      char* bp = pbase + qlocal * 128;
      pb[0][qf] = *(uint4*)(bp + (((unsigned)(lg * 16)) ^ sw));
      pb[1][qf] = *(uint4*)(bp + (((unsigned)(64 + lg * 16)) ^ sw));
    }
    // ---- O^T += V^T * P^T ----
#pragma unroll
    for (int df = 0; df < 8; ++df) {
      const bf16* vrow = Vp + (size_t)(df * 16 + lr) * SEQ + kv0 + lg * 8;
      uint4 va0 = *(const uint4*)(vrow);
      uint4 va1 = *(const uint4*)(vrow + 32);
      acc[df][0] = mfma16(va0, pb[0][0], acc[df][0]);
      acc[df][1] = mfma16(va0, pb[0][1], acc[df][1]);
      acc[df][0] = mfma16(va1, pb[1][0], acc[df][0]);
      acc[df][1] = mfma16(va1, pb[1][1], acc[df][1]);
    }
  }

  // ---- epilogue: normalize, write fp32 out[b][s][h*D + d] ----
#pragma unroll
  for (int qf = 0; qf < 2; ++qf) {
    float inv = 1.f / l_run[qf];
    size_t rowoff = ((size_t)b * SEQ + (size_t)(q0 + qf * 16 + lr)) * DMODEL + h * HD;
#pragma unroll
    for (int df = 0; df < 8; ++df) {
      float4 o;
      o.x = acc[df][qf][0] * inv;
      o.y = acc[df][qf][1] * inv;
      o.z = acc[df][qf][2] * inv;
      o.w = acc[df][qf][3] * inv;
      *(float4*)(out + rowoff + df * 16 + lg * 4) = o;
    }
  }
}

extern "C" void kernel_launch(void* const* d_in, const int* in_sizes, int n_in,
                              void* d_out, int out_size, void* d_ws, size_t ws_size,
                              hipStream_t stream) {
  const float* x = (const float*)d_in[0];
  const float* Wq = (const float*)d_in[1];
  const float* bq = (const float*)d_in[2];
  const float* Wk = (const float*)d_in[3];
  const float* bk = (const float*)d_in[4];
  const float* Wv = (const float*)d_in[5];
  const float* bv = (const float*)d_in[6];
  float* out = (float*)d_out;

  const size_t sz_x = (size_t)MROWS * DMODEL * 2;
  const size_t sz_w = (size_t)DMODEL * DMODEL * 2;
  const size_t sz_qkv = (size_t)MROWS * DMODEL * 2;
  if (ws_size < sz_x + 3 * sz_w + 3 * sz_qkv) return;

  char* w = (char*)d_ws;
  bf16* xb = (bf16*)w;  w += sz_x;
  bf16* WtQ = (bf16*)w; w += sz_w;
  bf16* WtK = (bf16*)w; w += sz_w;
  bf16* WtV = (bf16*)w; w += sz_w;
  bf16* Qb = (bf16*)w;  w += sz_qkv;
  bf16* Kb = (bf16*)w;  w += sz_qkv;
  bf16* Vtb = (bf16*)w; w += sz_qkv;

  cast_x_kernel<<<2048, 256, 0, stream>>>(x, xb, MROWS * DMODEL / 8);
  transpose_w_kernel<<<dim3(32, 32, 3), 256, 0, stream>>>(Wq, Wk, Wv, WtQ);
  gemm_bf16<<<dim3(64, 16), 256, 0, stream>>>(xb, WtQ, bq, Qb, 0);
  gemm_bf16<<<dim3(64, 16), 256, 0, stream>>>(xb, WtK, bk, Kb, 0);
  gemm_bf16<<<dim3(64, 16), 256, 0, stream>>>(xb, WtV, bv, Vtb, 1);
  attn_kernel<<<dim3(16, 64), 256, 0, stream>>>(Qb, Kb, Vtb, out);
}

// Round 2
// 636.506 us; speedup vs baseline: 1.3349x; 1.3349x over previous
//
#include <hip/hip_runtime.h>
#include <hip/hip_bf16.h>
#include <stdint.h>

#define DEVI __device__ __forceinline__

using bf16 = __hip_bfloat16;

typedef __bf16 bf16x8 __attribute__((ext_vector_type(8)));
typedef float f32x4 __attribute__((ext_vector_type(4)));

constexpr int BATCH = 4, NH = 16, SEQ = 2048, HD = 128, DMODEL = 2048;
constexpr int MROWS = BATCH * SEQ;  // 8192

DEVI f32x4 mfma16(uint4 a, uint4 b, f32x4 c) {
  return __builtin_amdgcn_mfma_f32_16x16x32_bf16(
      __builtin_bit_cast(bf16x8, a), __builtin_bit_cast(bf16x8, b), c, 0, 0, 0);
}

DEVI unsigned pack2(float a, float b) {
  __hip_bfloat16 ha = __float2bfloat16(a), hb = __float2bfloat16(b);
  unsigned short ua = __builtin_bit_cast(unsigned short, ha);
  unsigned short ub = __builtin_bit_cast(unsigned short, hb);
  return ((unsigned)ub << 16) | (unsigned)ua;
}

DEVI void gload16(const void* g, void* l) {
  auto gp = reinterpret_cast<__attribute__((address_space(1))) unsigned int*>(
      reinterpret_cast<uintptr_t>(g));
  auto lp = reinterpret_cast<__attribute__((address_space(3))) unsigned int*>(
      reinterpret_cast<uintptr_t>(l));
  __builtin_amdgcn_global_load_lds(gp, lp, 16, 0, 0);
}

// ---------------- cast x (fp32 -> bf16), vectorized ----------------
__global__ void cast_x_kernel(const float* __restrict__ in, bf16* __restrict__ out, int n8) {
  for (int i = blockIdx.x * blockDim.x + threadIdx.x; i < n8; i += gridDim.x * blockDim.x) {
    const float4* p = (const float4*)in + (size_t)i * 2;
    float4 a = p[0], b = p[1];
    uint4 u;
    u.x = pack2(a.x, a.y);
    u.y = pack2(a.z, a.w);
    u.z = pack2(b.x, b.y);
    u.w = pack2(b.z, b.w);
    *((uint4*)out + i) = u;
  }
}

// ------------- transpose-cast W [K][N] fp32 -> Wt [N][K] bf16 -------------
__global__ void transpose_w_kernel(const float* __restrict__ W0, const float* __restrict__ W1,
                                   const float* __restrict__ W2, bf16* __restrict__ WtBase) {
  const int z = blockIdx.z;
  const float* W = (z == 0) ? W0 : (z == 1) ? W1 : W2;
  bf16* Wt = WtBase + (size_t)z * DMODEL * DMODEL;
  __shared__ float tile[64][65];
  const int k0 = blockIdx.x * 64, n0 = blockIdx.y * 64;
  const int tid = threadIdx.x;
  for (int i = tid; i < 4096; i += 256) {
    int r = i >> 6, c = i & 63;
    tile[r][c] = W[(size_t)(k0 + r) * DMODEL + n0 + c];
  }
  __syncthreads();
  for (int i = tid; i < 4096; i += 256) {
    int r = i >> 6, c = i & 63;  // r = n index, c = k index
    Wt[(size_t)(n0 + r) * DMODEL + k0 + c] = __float2bfloat16(tile[c][r]);
  }
}

// ---------------- bf16 GEMM: C[m][n] = sum_k A[m][k] * Bt[n][k] + bias[n] ---------------
__global__ __launch_bounds__(256) void gemm_bf16(
    const bf16* __restrict__ A, const bf16* __restrict__ Bt,
    const float* __restrict__ bias, bf16* __restrict__ Cout, int transposed) {
  __shared__ __align__(16) bf16 As[128][32];
  __shared__ __align__(16) bf16 Bs[128][32];
  const int tid = threadIdx.x;
  const int lane = tid & 63, wave = tid >> 6;
  const int lr = lane & 15, lg = lane >> 4;
  const int m0 = blockIdx.x * 128, n0 = blockIdx.y * 128;
  const int wr = wave >> 1, wc = wave & 1;

  f32x4 acc[4][4];
#pragma unroll
  for (int i = 0; i < 4; ++i)
#pragma unroll
    for (int j = 0; j < 4; ++j) acc[i][j] = (f32x4){0.f, 0.f, 0.f, 0.f};

  const char* ag = (const char*)(A + (size_t)(m0 + (tid >> 2)) * DMODEL) + (tid & 3) * 16;
  const char* bg = (const char*)(Bt + (size_t)(n0 + (tid >> 2)) * DMODEL) + (tid & 3) * 16;
  char* asw = (char*)As + wave * 1024;
  char* bsw = (char*)Bs + wave * 1024;
  constexpr size_t rowadv = (size_t)64 * DMODEL * 2;

  for (int k0 = 0; k0 < DMODEL; k0 += 32) {
    gload16(ag + k0 * 2, asw);
    gload16(ag + k0 * 2 + rowadv, asw + 4096);
    gload16(bg + k0 * 2, bsw);
    gload16(bg + k0 * 2 + rowadv, bsw + 4096);
    __syncthreads();
    uint4 af[4], bfr[4];
#pragma unroll
    for (int i = 0; i < 4; ++i) af[i] = *(const uint4*)&As[wr * 64 + i * 16 + lr][lg * 8];
#pragma unroll
    for (int j = 0; j < 4; ++j) bfr[j] = *(const uint4*)&Bs[wc * 64 + j * 16 + lr][lg * 8];
#pragma unroll
    for (int i = 0; i < 4; ++i)
#pragma unroll
      for (int j = 0; j < 4; ++j) acc[i][j] = mfma16(af[i], bfr[j], acc[i][j]);
    __syncthreads();
  }

  float bvals[4];
#pragma unroll
  for (int nf = 0; nf < 4; ++nf) bvals[nf] = bias[n0 + wc * 64 + nf * 16 + lr];

  const int bh = ((m0 >> 11) << 4) | (n0 >> 7);
  const int sbase = (m0 & 2047) + wr * 64;
  if (!transposed) {
    bf16* base = Cout + (size_t)bh * SEQ * HD;
#pragma unroll
    for (int mf = 0; mf < 4; ++mf)
#pragma unroll
      for (int nf = 0; nf < 4; ++nf) {
        int d = wc * 64 + nf * 16 + lr;
#pragma unroll
        for (int jj = 0; jj < 4; ++jj) {
          int s = sbase + mf * 16 + lg * 4 + jj;
          base[(size_t)s * HD + d] = __float2bfloat16(acc[mf][nf][jj] + bvals[nf]);
        }
      }
  } else {
    bf16* base = Cout + (size_t)bh * HD * SEQ;
#pragma unroll
    for (int mf = 0; mf < 4; ++mf)
#pragma unroll
      for (int nf = 0; nf < 4; ++nf) {
        int d = wc * 64 + nf * 16 + lr;
        int s0 = sbase + mf * 16 + lg * 4;
        uint2 u;
        u.x = pack2(acc[mf][nf][0] + bvals[nf], acc[mf][nf][1] + bvals[nf]);
        u.y = pack2(acc[mf][nf][2] + bvals[nf], acc[mf][nf][3] + bvals[nf]);
        *(uint2*)&base[(size_t)d * SEQ + s0] = u;
      }
  }
}

// ---------------- flash attention, causal, LDS-staged + paired tiles ----------------
// Q,K: [BH][S][D] bf16;  Vt: [BH][D][S] bf16;  out: [B][S][H*D] fp32
// 4 waves/block, 32 q-rows/wave. Block does q-tile pair (pi, 15-pi) of one bh
// sequentially -> uniform work (34 kv-tiles per block). K/V^T kv-tiles (64 kv)
// staged in double-buffered XOR-swizzled LDS via global_load_lds, shared by waves.
__global__ __launch_bounds__(256) void attn_kernel(
    const bf16* __restrict__ Q, const bf16* __restrict__ K,
    const bf16* __restrict__ Vt, float* __restrict__ out) {
  extern __shared__ __align__(16) char smem[];
  char* KsB = smem;            // 2 x 16384  (K tile [64][128] bf16, swizzled)
  char* VsB = smem + 32768;    // 2 x 16384  (V^T tile [128][64] bf16, swizzled)
  char* plB = smem + 65536;    // 4 x 4096   (per-wave P buffer)

  const int tid = threadIdx.x;
  const int lane = tid & 63;
  const int wave = tid >> 6;
  const int lr = lane & 15, lg = lane >> 4;
  const unsigned swl = ((unsigned)(lr & 7)) << 4;

  // 512 blocks: group all 8 pairs of one bh on one XCD (L2 locality).
  const int lid = blockIdx.x;
  const int xcd = lid & 7, slot = lid >> 3;       // slot 0..63
  const int bh = xcd * 8 + (slot >> 3);
  const int pi = slot & 7;                        // pair index 0..7
  const int b = bh >> 4, h = bh & 15;

  const bf16* Qp = Q + (size_t)bh * SEQ * HD;
  const char* Kg0 = (const char*)(K + (size_t)bh * SEQ * HD);
  const char* Vg0 = (const char*)(Vt + (size_t)bh * HD * SEQ);
  char* pbase = plB + wave * 4096;

  const float C2 = 0.08838834764831845f * 1.44269504088896f;  // 1/sqrt(128) * log2(e)
  int cur = 0;

  for (int sec = 0; sec < 2; ++sec) {
    const int qt = (sec == 0) ? pi : (15 - pi);   // q-tile (128 rows)
    const int q0 = qt * 128 + wave * 32;
    const int nt = 2 * qt + 2;                    // block kv-tile count
    const int nt_w = (q0 + 95) >> 6;              // this wave's useful tiles

    // Q fragments (B-operand): q col = lr, d chunk = dc*32 + lg*8
    uint4 qfrag[2][4];
#pragma unroll
    for (int qf = 0; qf < 2; ++qf) {
      const bf16* qrow = Qp + (size_t)(q0 + qf * 16 + lr) * HD + lg * 8;
#pragma unroll
      for (int dc = 0; dc < 4; ++dc) qfrag[qf][dc] = *(const uint4*)(qrow + dc * 32);
    }

    f32x4 acc[8][2];
#pragma unroll
    for (int df = 0; df < 8; ++df) {
      acc[df][0] = (f32x4){0.f, 0.f, 0.f, 0.f};
      acc[df][1] = (f32x4){0.f, 0.f, 0.f, 0.f};
    }
    float m_run[2] = {-1e30f, -1e30f};
    float l_run[2] = {0.f, 0.f};
    const int qg[2] = {q0 + lr, q0 + 16 + lr};

    // ---- prologue stage: tile 0 -> buf[cur] ----
    {
      const char* Kg = Kg0;
      const char* Vg = Vg0;
      char* kl = KsB + cur * 16384 + wave * 1024;
      char* vl = VsB + cur * 16384 + wave * 1024;
#pragma unroll
      for (int r = 0; r < 4; ++r) {
        int o = r * 4096 + tid * 16;
        int krow = o >> 8; unsigned kcb = o & 255;
        gload16(Kg + krow * 256 + (kcb ^ (((unsigned)(krow & 7)) << 4)), kl + r * 4096);
        int vrow = o >> 7; unsigned vcb = o & 127;
        gload16(Vg + (size_t)vrow * 4096 + (vcb ^ (((unsigned)(vrow & 7)) << 4)), vl + r * 4096);
      }
    }
    __syncthreads();  // compiler drains vmcnt(0) before s_barrier

    for (int t = 0; t < nt; ++t) {
      // ---- stage next tile into buf[cur^1] (overlaps with compute below) ----
      if (t + 1 < nt) {
        const char* Kg = Kg0 + ((size_t)(t + 1) << 14);   // (t+1)*64 rows * 256 B
        const char* Vg = Vg0 + ((size_t)(t + 1) << 7);    // (t+1)*64 kv * 2 B
        char* kl = KsB + (cur ^ 1) * 16384 + wave * 1024;
        char* vl = VsB + (cur ^ 1) * 16384 + wave * 1024;
#pragma unroll
        for (int r = 0; r < 4; ++r) {
          int o = r * 4096 + tid * 16;
          int krow = o >> 8; unsigned kcb = o & 255;
          gload16(Kg + krow * 256 + (kcb ^ (((unsigned)(krow & 7)) << 4)), kl + r * 4096);
          int vrow = o >> 7; unsigned vcb = o & 127;
          gload16(Vg + (size_t)vrow * 4096 + (vcb ^ (((unsigned)(vrow & 7)) << 4)), vl + r * 4096);
        }
      }

      if (t < nt_w) {  // wave-uniform: skip fully-masked tiles, still hit barriers
        const int kv0 = t << 6;
        const char* kb = KsB + cur * 16384;
        const char* vb = VsB + cur * 16384;

        // ---- S^T = K * Q^T ----
        f32x4 sfr[4][2];
#pragma unroll
        for (int kvf = 0; kvf < 4; ++kvf) {
          sfr[kvf][0] = (f32x4){0.f, 0.f, 0.f, 0.f};
          sfr[kvf][1] = (f32x4){0.f, 0.f, 0.f, 0.f};
          const char* krow = kb + (kvf * 16 + lr) * 256;
#pragma unroll
          for (int dc = 0; dc < 4; ++dc) {
            uint4 ka = *(const uint4*)(krow + (((unsigned)(dc * 64 + lg * 16)) ^ swl));
            sfr[kvf][0] = mfma16(ka, qfrag[0][dc], sfr[kvf][0]);
            sfr[kvf][1] = mfma16(ka, qfrag[1][dc], sfr[kvf][1]);
          }
        }

        // ---- online softmax (base-2 domain) ----
        const bool need_mask = (kv0 + 63) > q0;
#pragma unroll
        for (int qf = 0; qf < 2; ++qf) {
          float mx = -1e30f;
#pragma unroll
          for (int kvf = 0; kvf < 4; ++kvf)
#pragma unroll
            for (int j = 0; j < 4; ++j) {
              float v = sfr[kvf][qf][j] * C2;
              if (need_mask) {
                int kvgl = kv0 + kvf * 16 + lg * 4 + j;
                v = (kvgl <= qg[qf]) ? v : -1e30f;
              }
              sfr[kvf][qf][j] = v;
              mx = fmaxf(mx, v);
            }
          mx = fmaxf(mx, __shfl_xor(mx, 16));
          mx = fmaxf(mx, __shfl_xor(mx, 32));
          float mnew = fmaxf(m_run[qf], mx);
          float corr = exp2f(m_run[qf] - mnew);
          m_run[qf] = mnew;
          float ps = 0.f;
          const int qlocal = qf * 16 + lr;
          const unsigned sw = ((unsigned)(qlocal & 7)) << 4;
          char* bp = pbase + qlocal * 128;
#pragma unroll
          for (int kvf = 0; kvf < 4; ++kvf) {
            float p0 = exp2f(sfr[kvf][qf][0] - mnew);
            float p1 = exp2f(sfr[kvf][qf][1] - mnew);
            float p2 = exp2f(sfr[kvf][qf][2] - mnew);
            float p3 = exp2f(sfr[kvf][qf][3] - mnew);
            ps += p0 + p1 + p2 + p3;
            unsigned off = ((unsigned)(kvf * 32 + lg * 8)) ^ sw;
            *(unsigned*)(bp + off) = pack2(p0, p1);
            *(unsigned*)(bp + off + 4) = pack2(p2, p3);
          }
          ps += __shfl_xor(ps, 16);
          ps += __shfl_xor(ps, 32);
          l_run[qf] = l_run[qf] * corr + ps;
#pragma unroll
          for (int df = 0; df < 8; ++df) acc[df][qf] *= corr;
        }
        // cross-lane LDS RAW within wave: drain DS queue, fence compiler reordering
        asm volatile("s_waitcnt lgkmcnt(0)" ::: "memory");

        // ---- read P^T B-fragments ----
        uint4 pb[2][2];  // [kc][qf]
#pragma unroll
        for (int qf = 0; qf < 2; ++qf) {
          const int qlocal = qf * 16 + lr;
          const unsigned sw = ((unsigned)(qlocal & 7)) << 4;
          char* bp = pbase + qlocal * 128;
          pb[0][qf] = *(uint4*)(bp + (((unsigned)(lg * 16)) ^ sw));
          pb[1][qf] = *(uint4*)(bp + (((unsigned)(64 + lg * 16)) ^ sw));
        }

        // ---- O^T += V^T * P^T ----
#pragma unroll
        for (int df = 0; df < 8; ++df) {
          const char* vrow = vb + (df * 16 + lr) * 128;
          uint4 va0 = *(const uint4*)(vrow + (((unsigned)(lg * 16)) ^ swl));
          uint4 va1 = *(const uint4*)(vrow + (((unsigned)(64 + lg * 16)) ^ swl));
          acc[df][0] = mfma16(va0, pb[0][0], acc[df][0]);
          acc[df][1] = mfma16(va0, pb[0][1], acc[df][1]);
          acc[df][0] = mfma16(va1, pb[1][0], acc[df][0]);
          acc[df][1] = mfma16(va1, pb[1][1], acc[df][1]);
        }
      }

      __syncthreads();  // drains vmcnt(0): next buffer complete; cur safe to overwrite
      cur ^= 1;
    }

    // ---- epilogue: normalize, write fp32 out[b][s][h*D + d] ----
#pragma unroll
    for (int qf = 0; qf < 2; ++qf) {
      float inv = 1.f / l_run[qf];
      size_t rowoff = ((size_t)b * SEQ + (size_t)(q0 + qf * 16 + lr)) * DMODEL + h * HD;
#pragma unroll
      for (int df = 0; df < 8; ++df) {
        float4 o;
        o.x = acc[df][qf][0] * inv;
        o.y = acc[df][qf][1] * inv;
        o.z = acc[df][qf][2] * inv;
        o.w = acc[df][qf][3] * inv;
        *(float4*)(out + rowoff + df * 16 + lg * 4) = o;
      }
    }
  }
}

extern "C" void kernel_launch(void* const* d_in, const int* in_sizes, int n_in,
                              void* d_out, int out_size, void* d_ws, size_t ws_size,
                              hipStream_t stream) {
  const float* x = (const float*)d_in[0];
  const float* Wq = (const float*)d_in[1];
  const float* bq = (const float*)d_in[2];
  const float* Wk = (const float*)d_in[3];
  const float* bk = (const float*)d_in[4];
  const float* Wv = (const float*)d_in[5];
  const float* bv = (const float*)d_in[6];
  float* out = (float*)d_out;

  const size_t sz_x = (size_t)MROWS * DMODEL * 2;
  const size_t sz_w = (size_t)DMODEL * DMODEL * 2;
  const size_t sz_qkv = (size_t)MROWS * DMODEL * 2;
  if (ws_size < sz_x + 3 * sz_w + 3 * sz_qkv) return;

  char* w = (char*)d_ws;
  bf16* xb = (bf16*)w;  w += sz_x;
  bf16* WtQ = (bf16*)w; w += sz_w;
  bf16* WtK = (bf16*)w; w += sz_w;
  bf16* WtV = (bf16*)w; w += sz_w;
  bf16* Qb = (bf16*)w;  w += sz_qkv;
  bf16* Kb = (bf16*)w;  w += sz_qkv;
  bf16* Vtb = (bf16*)w; w += sz_qkv;

  cast_x_kernel<<<2048, 256, 0, stream>>>(x, xb, MROWS * DMODEL / 8);
  transpose_w_kernel<<<dim3(32, 32, 3), 256, 0, stream>>>(Wq, Wk, Wv, WtQ);
  gemm_bf16<<<dim3(64, 16), 256, 0, stream>>>(xb, WtQ, bq, Qb, 0);
  gemm_bf16<<<dim3(64, 16), 256, 0, stream>>>(xb, WtK, bk, Kb, 0);
  gemm_bf16<<<dim3(64, 16), 256, 0, stream>>>(xb, WtV, bv, Vtb, 1);
  attn_kernel<<<dim3(512), 256, 81920, stream>>>(Qb, Kb, Vtb, out);
}